// Round 5
// baseline (148.831 us; speedup 1.0000x reference)
//
#include <hip/hip_runtime.h>
#include <math.h>

typedef __attribute__((ext_vector_type(8))) short short8;
typedef __attribute__((ext_vector_type(16))) float f32x16;
typedef unsigned short ushortT;

#define NB     16
#define CIN    512
#define TT     2048
#define COUT2  1024
#define NSTYLE 128
#define KKTOT  1536      // 3 * 512
#define TPAD   2050      // T + 2 pad rows
#define NKT    24        // K-tiles of 64

#define SCALE_LIN  0.088388347648318447f
#define SCALE_CONV 0.014731391274719736f

__device__ __forceinline__ ushortT f2bf(float f) {
  union { float f; unsigned u; } v; v.f = f;
  unsigned r = v.u + 0x7fffu + ((v.u >> 16) & 1u);
  return (ushortT)(r >> 16);
}

__device__ __forceinline__ void gload16(const void* g, void* l) {
  __builtin_amdgcn_global_load_lds(
      (const __attribute__((address_space(1))) void*)g,
      (__attribute__((address_space(3))) void*)l, 16, 0, 0);
}

// ---------------- s / beta + pad-row zeroing ----------------
__global__ void style_kernel(const float* __restrict__ c_trg,
                             const float* __restrict__ w_s, const float* __restrict__ b_s,
                             const float* __restrict__ w_b, const float* __restrict__ b_b,
                             float* __restrict__ s, float* __restrict__ beta,
                             ushortT* __restrict__ xT) {
  int gid = blockIdx.x * 256 + threadIdx.x;   // 0..8191 = b*512 + ci
  int b = gid >> 9, ci = gid & 511;
  const float* ct = c_trg + b * NSTYLE;
  const float* ws = w_s + ci * NSTYLE;
  const float* wb = w_b + ci * NSTYLE;
  float as = 0.f, ab = 0.f;
#pragma unroll 8
  for (int j = 0; j < NSTYLE; ++j) {
    float c = ct[j];
    as += c * ws[j];
    ab += c * wb[j];
  }
  s[gid]    = as * SCALE_LIN + b_s[ci];
  beta[gid] = ab * SCALE_LIN + b_b[ci];
  xT[(size_t)b * TPAD * CIN + ci] = 0;
  xT[((size_t)b * TPAD + TPAD - 1) * CIN + ci] = 0;
}

// ---------------- x [b][ci][t] f32 -> xT [b][t+1][ci] bf16 ----------------
__global__ void xpose_kernel(const float* __restrict__ x, ushortT* __restrict__ xT) {
  int b = blockIdx.z, ct = blockIdx.y, tt = blockIdx.x;
  int t0 = tt * 64, ci0 = ct * 64;
  __shared__ float tile[64][65];
  const float* xB = x + (size_t)b * CIN * TT;
  int rr = threadIdx.x >> 4;   // 0..15
  int c4 = threadIdx.x & 15;   // 0..15
#pragma unroll
  for (int it = 0; it < 4; ++it) {
    int ci = rr + it * 16;
    float4 v = *(const float4*)(xB + (size_t)(ci0 + ci) * TT + t0 + c4 * 4);
    tile[ci][c4 * 4 + 0] = v.x; tile[ci][c4 * 4 + 1] = v.y;
    tile[ci][c4 * 4 + 2] = v.z; tile[ci][c4 * 4 + 3] = v.w;
  }
  __syncthreads();
  ushortT* xTB = xT + (size_t)b * TPAD * CIN;
#pragma unroll
  for (int it = 0; it < 4; ++it) {
    int t = rr + it * 16;
    ushort4 o;
    o.x = f2bf(tile[c4 * 4 + 0][t]); o.y = f2bf(tile[c4 * 4 + 1][t]);
    o.z = f2bf(tile[c4 * 4 + 2][t]); o.w = f2bf(tile[c4 * 4 + 3][t]);
    *(ushort4*)(xTB + (size_t)(1 + t0 + t) * CIN + ci0 + c4 * 4) = o;
  }
}

// ---------------- modulate + demod-normalize weights -> bf16 ----------------
__global__ void modw_kernel(const float* __restrict__ weight,
                            const float* __restrict__ s, const float* __restrict__ beta,
                            ushortT* __restrict__ wnorm) {
  int co = blockIdx.x, b = blockIdx.y, tid = threadIdx.x;  // 256 threads, 2 ci each
  int ci = tid * 2;
  const float* wp = weight + (size_t)co * CIN * 3 + (size_t)ci * 3;
  float s0 = s[b * CIN + ci],     s1 = s[b * CIN + ci + 1];
  float e0 = beta[b * CIN + ci],  e1 = beta[b * CIN + ci + 1];
  float w0 = SCALE_CONV * (wp[0] * s0 + e0);
  float w1 = SCALE_CONV * (wp[1] * s0 + e0);
  float w2 = SCALE_CONV * (wp[2] * s0 + e0);
  float w3 = SCALE_CONV * (wp[3] * s1 + e1);
  float w4 = SCALE_CONV * (wp[4] * s1 + e1);
  float w5 = SCALE_CONV * (wp[5] * s1 + e1);
  float sum = w0 + w1 + w2 + w3 + w4 + w5;
  float sq  = w0*w0 + w1*w1 + w2*w2 + w3*w3 + w4*w4 + w5*w5;
#pragma unroll
  for (int off = 32; off; off >>= 1) {
    sum += __shfl_xor(sum, off);
    sq  += __shfl_xor(sq,  off);
  }
  __shared__ float rs[4], rq[4];
  if ((tid & 63) == 0) { rs[tid >> 6] = sum; rq[tid >> 6] = sq; }
  __syncthreads();
  float tsum = rs[0] + rs[1] + rs[2] + rs[3];
  float tsq  = rq[0] + rq[1] + rq[2] + rq[3];
  float mean  = tsum * (1.0f / 1536.0f);
  float demod = rsqrtf(tsq + 1e-8f);
  int r = ((co & 511) << 1) | (co >> 9);
  ushortT* dst = wnorm + ((size_t)b * COUT2 + r) * KKTOT;
  ushort2 p0, p1, p2;
  p0.x = f2bf((w0 - mean) * demod); p0.y = f2bf((w3 - mean) * demod);
  p1.x = f2bf((w1 - mean) * demod); p1.y = f2bf((w4 - mean) * demod);
  p2.x = f2bf((w2 - mean) * demod); p2.y = f2bf((w5 - mean) * demod);
  *(ushort2*)(dst +        ci) = p0;
  *(ushort2*)(dst +  512 + ci) = p1;
  *(ushort2*)(dst + 1024 + ci) = p2;
}

// ---------------- main conv-as-GEMM: 256^2 tile, 4-phase, 32x32x16 MFMA ----------------
// LDS regions: ridx = d*4 + op*2 + ks, region = [256 rows][32 cols] bf16 = 16384 B.
// Rows 64B = 4x16B blocks XOR-swizzled by (row>>1)&3. 8 regions = 128 KiB.
// Staging identical to R3/R4 (proven). Compute: 32x32x16 MFMA, per wave 4Mx2N tiles.

#define AF(d, s, m, k) (*(const short8*)(ldsc + ((d) * 4 + (s)) * 16384 + arow + (m) * 2048 + ((k) ? colk1 : colk0)))
#define BF(d, s, n, k) (*(const short8*)(ldsc + ((d) * 4 + 2 + (s)) * 16384 + brow + (n) * 2048 + ((k) ? colk1 : colk0)))

#define STAGE_A(d, s, kt) do { int kc_ = (kt) * 64 + (s) * 32;                  \
    gload16(sA0 + kc_, ldsw + ((d) * 4 + (s)) * 8192 + dst8);                   \
    gload16(sA1 + kc_, ldsw + ((d) * 4 + (s)) * 8192 + 4096 + dst8);            \
  } while (0)

#define STAGE_B(d, s, kt) do { int kc_ = (kt) * 64 + (s) * 32;                  \
    gload16(sB0 + kc_, ldsw + ((d) * 4 + 2 + (s)) * 8192 + dst8);               \
    gload16(sB1 + kc_, ldsw + ((d) * 4 + 2 + (s)) * 8192 + 4096 + dst8);        \
  } while (0)

// PHASE: [12 ds_reads][stages][vmcnt][barrier][16 MFMA][barrier]
// VMN: 8/4/0 -> s_waitcnt vmcnt(N); -1 -> none
#define PHASE(d, s, STAGES, VMN) do {                                           \
    short8 af[4][2], bfr[2][2];                                                 \
    _Pragma("unroll") for (int m_ = 0; m_ < 4; ++m_) {                          \
      af[m_][0] = AF(d, s, m_, 0); af[m_][1] = AF(d, s, m_, 1);                 \
    }                                                                           \
    _Pragma("unroll") for (int n_ = 0; n_ < 2; ++n_) {                          \
      bfr[n_][0] = BF(d, s, n_, 0); bfr[n_][1] = BF(d, s, n_, 1);               \
    }                                                                           \
    STAGES;                                                                     \
    if ((VMN) == 8)      asm volatile("s_waitcnt vmcnt(8)" ::: "memory");       \
    else if ((VMN) == 4) asm volatile("s_waitcnt vmcnt(4)" ::: "memory");       \
    else if ((VMN) == 0) asm volatile("s_waitcnt vmcnt(0)" ::: "memory");       \
    __builtin_amdgcn_sched_barrier(0);                                          \
    __builtin_amdgcn_s_barrier();                                               \
    __builtin_amdgcn_sched_barrier(0);                                          \
    __builtin_amdgcn_s_setprio(1);                                              \
    _Pragma("unroll") for (int k_ = 0; k_ < 2; ++k_)                            \
      _Pragma("unroll") for (int m_ = 0; m_ < 4; ++m_)                          \
        _Pragma("unroll") for (int n_ = 0; n_ < 2; ++n_)                        \
          acc[m_][n_] = __builtin_amdgcn_mfma_f32_32x32x16_bf16(                \
              af[m_][k_], bfr[n_][k_], acc[m_][n_], 0, 0, 0);                   \
    __builtin_amdgcn_s_setprio(0);                                              \
    __builtin_amdgcn_sched_barrier(0);                                          \
    __builtin_amdgcn_s_barrier();                                               \
    __builtin_amdgcn_sched_barrier(0);                                          \
  } while (0)

__global__ __launch_bounds__(512, 2)
void conv_gemm8(const ushortT* __restrict__ wnorm, const ushortT* __restrict__ xT,
                float* __restrict__ out) {
  extern __shared__ ushortT ldsw[];
  const char* ldsc = (const char*)ldsw;

  // XCD-chunked bijective swizzle (512 blocks % 8 == 0)
  int orig = blockIdx.x;
  int wgid = (orig & 7) * 64 + (orig >> 3);
  int b  = wgid >> 5;
  int i5 = wgid & 31;
  int mp = i5 >> 4, r2 = i5 & 15;
  int nt = r2 >> 1, mt = mp * 2 + (r2 & 1);
  int co0 = mt * 256, t0 = nt * 256;

  int tid = threadIdx.x;
  int l = tid & 63, w = tid >> 6;
  int wm = w & 1, wn = w >> 1;           // 2 x 4 wave grid

  // staging constants (identical to R3/R4)
  int r0 = tid >> 2;
  int jbs8 = (((tid & 3) ^ ((r0 >> 1) & 3)) << 3);
  int dst8 = tid * 8;
  // ds_read constants for 32x32 fragments
  int sw = (l >> 1) & 3;                         // = ((row>>1)&3) for row≡(l&31) mod 32
  int arow = (wm * 128 + (l & 31)) * 64;
  int brow = (wn * 64  + (l & 31)) * 64;
  int colk0 = (((l >> 5)    ) ^ sw) * 16;
  int colk1 = (((l >> 5) | 2) ^ sw) * 16;

  const ushortT* wB = wnorm + (size_t)b * COUT2 * KKTOT;
  const ushortT* xB = xT + (size_t)b * TPAD * CIN;
  const ushortT* sA0 = wB + (size_t)(co0 + r0) * KKTOT + jbs8;
  const ushortT* sA1 = sA0 + (size_t)128 * KKTOT;
  // tap*CIN + ci == kk exactly (CIN==512), so B staging is a flat kc offset too
  const ushortT* sB0 = xB + (size_t)(t0 + r0) * CIN + jbs8;
  const ushortT* sB1 = sB0 + (size_t)128 * CIN;

  f32x16 acc[4][2] = {};

  // prologue: d0 both halves (kt0=0), d1 ks0 (kt1=1)
  STAGE_A(0, 0, 0); STAGE_B(0, 0, 0);
  STAGE_A(0, 1, 0); STAGE_B(0, 1, 0);
  STAGE_A(1, 0, 1); STAGE_B(1, 0, 1);
  asm volatile("s_waitcnt vmcnt(8)" ::: "memory");
  __builtin_amdgcn_sched_barrier(0);
  __builtin_amdgcn_s_barrier();
  __builtin_amdgcn_sched_barrier(0);

  for (int j = 0; j < 11; ++j) {
    int kt1 = 2 * j + 1;
    int k0n = 2 * j + 2, k1n = 2 * j + 3;
    PHASE(0, 0, { STAGE_A(1, 1, kt1); STAGE_B(1, 1, kt1); }, 8);
    PHASE(0, 1, { STAGE_A(0, 0, k0n); STAGE_B(0, 0, k0n); }, 8);
    PHASE(1, 0, { STAGE_A(0, 1, k0n); STAGE_B(0, 1, k0n); }, 8);
    PHASE(1, 1, { STAGE_A(1, 0, k1n); STAGE_B(1, 0, k1n); }, 8);
  }
  // peeled final iteration (kt 22 in d0, kt 23 in d1)
  PHASE(0, 0, { STAGE_A(1, 1, 23); STAGE_B(1, 1, 23); }, 8);
  PHASE(0, 1, {}, 4);
  PHASE(1, 0, {}, 0);
  PHASE(1, 1, {}, -1);

  // epilogue: C/D 32x32 layout col=lane&31, row=(reg&3)+8*(reg>>2)+4*(lane>>5).
  // Interleaved co' rows: regs (2q,2q+1) = (a,g) of channel (cobase+row)/2.
  int hi4 = (l >> 5) * 4;
#pragma unroll
  for (int m = 0; m < 4; ++m) {
    int cobase = co0 + wm * 128 + m * 32;
#pragma unroll
    for (int n = 0; n < 2; ++n) {
      int t = t0 + wn * 64 + n * 32 + (l & 31);
      f32x16 v = acc[m][n];
#pragma unroll
      for (int q = 0; q < 8; ++q) {
        int row = 2 * (q & 1) + 8 * (q >> 1) + hi4;
        int c = (cobase + row) >> 1;
        float a = v[2 * q], g = v[2 * q + 1];
        out[((size_t)b * (COUT2 / 2) + c) * TT + t] = a / (1.f + __expf(-g));
      }
    }
  }
}

extern "C" void kernel_launch(void* const* d_in, const int* in_sizes, int n_in,
                              void* d_out, int out_size, void* d_ws, size_t ws_size,
                              hipStream_t stream) {
  const float* x      = (const float*)d_in[0];
  const float* c_trg  = (const float*)d_in[2];
  const float* w_s    = (const float*)d_in[3];
  const float* b_s    = (const float*)d_in[4];
  const float* w_b    = (const float*)d_in[5];
  const float* b_b    = (const float*)d_in[6];
  const float* weight = (const float*)d_in[7];
  float* out = (float*)d_out;

  char* ws = (char*)d_ws;
  float*   s     = (float*)ws;                           // 32 KB
  float*   beta  = (float*)(ws + 32768);                 // 32 KB
  ushortT* xT    = (ushortT*)(ws + 65536);               // 33,587,200 B
  ushortT* wnorm = (ushortT*)(ws + 65536 + 33587200);    // 50,331,648 B

  hipFuncSetAttribute((const void*)conv_gemm8,
                      hipFuncAttributeMaxDynamicSharedMemorySize, 131072);

  style_kernel<<<32, 256, 0, stream>>>(c_trg, w_s, b_s, w_b, b_b, s, beta, xT);
  xpose_kernel<<<dim3(32, 8, 16), 256, 0, stream>>>(x, xT);
  modw_kernel<<<dim3(1024, 16), 256, 0, stream>>>(weight, s, beta, wnorm);
  conv_gemm8<<<512, 512, 131072, stream>>>(wnorm, xT, out);
}